// Round 4
// baseline (256.077 us; speedup 1.0000x reference)
//
#include <hip/hip_runtime.h>
#include <hip/hip_bf16.h>

// Problem constants
#define NN 128
#define CC 64
#define TT 128
#define VV 25
#define RR 8
#define HH 12
#define TPAD 132   // xs row stride (dwords): %4==0 for b128 align; /4=33 odd -> quads cycle all 8
#define ADSZ 784   // 28*28 padded Ad' tile (floats)

// ---------------------------------------------------------------------------
// Kernel A: xm[n,c,v] = mean over T of x[n,c,t,v].  One block per (n,c).
// ---------------------------------------------------------------------------
__global__ __launch_bounds__(256) void kA_tmean(const float* __restrict__ x,
                                                float* __restrict__ xm) {
    const int blk = blockIdx.x;            // n*CC + c
    const int tid = threadIdx.x;
    __shared__ float st[TT * VV];          // 3200 floats
    __shared__ float ps[8 * VV];

    const float4* xb4 = (const float4*)(x + (size_t)blk * (TT * VV));
    float4* st4 = (float4*)st;
    for (int i = tid; i < (TT * VV) / 4; i += 256) st4[i] = xb4[i];
    __syncthreads();

    if (tid < 200) {
        const int v = tid % VV, tseg = tid / VV;   // 8 segments of 16 t
        float s = 0.f;
        const int base = tseg * 16 * VV + v;
#pragma unroll
        for (int i = 0; i < 16; i++) s += st[base + i * VV];
        ps[tseg * VV + v] = s;
    }
    __syncthreads();
    if (tid < VV) {
        float s = 0.f;
#pragma unroll
        for (int k = 0; k < 8; k++) s += ps[k * VV + tid];
        xm[(size_t)blk * VV + tid] = s * (1.f / TT);
    }
}

// ---------------------------------------------------------------------------
// Kernel B2: per-(n, c-half) block. Computes the whole Ad' pipeline:
//  s, SE attention a[v]; x1/x2; rel (tanh) in LDS (never hits HBM);
//  Ad'[c][u][v] = (b4[c] + A[u,v] + sum_r w4[c,r]*rel[r,u,v]) * a[v]
// written to ws as padded 28x28 tiles (zeros outside 25x25), float4 stores.
// R3 lesson: kC's per-block rel gather (6272 scalar L2 loads + 8 FMA/uv)
// was its VALU/TA tail — hoist it here where rel is computed once per n.
// ---------------------------------------------------------------------------
__global__ __launch_bounds__(256) void kB2_adbuild(
    const float* __restrict__ xm, const float* __restrict__ A,
    const float* __restrict__ w1, const float* __restrict__ b1,
    const float* __restrict__ w2, const float* __restrict__ b2,
    const float* __restrict__ w4, const float* __restrict__ b4,
    const float* __restrict__ sw1, const float* __restrict__ sb1,
    const float* __restrict__ sw2, const float* __restrict__ sb2,
    float* __restrict__ ad_ws) {
    const int n = blockIdx.x >> 1;
    const int chalf = blockIdx.x & 1;      // c in [chalf*32, chalf*32+32)
    const int tid = threadIdx.x;

    __shared__ float lxm[CC * VV];     // 1600
    __shared__ float lA[VV * VV];      // 625
    __shared__ float lw4[CC * RR];     // 512
    __shared__ float lb4[CC];          // 64
    __shared__ float ls[VV];
    __shared__ float lh[HH];
    __shared__ float la[VV];
    __shared__ float l1[RR * VV];      // 200
    __shared__ float l2[RR * VV];      // 200
    __shared__ float lrel[RR * VV * VV]; // 5000

    for (int i = tid; i < CC * VV; i += 256) lxm[i] = xm[(size_t)n * CC * VV + i];
    for (int i = tid; i < VV * VV; i += 256) lA[i] = A[i];
    for (int i = tid; i < CC * RR; i += 256) lw4[i] = w4[i];
    if (tid < CC) lb4[tid] = b4[tid];
    __syncthreads();

    if (tid < VV) {
        float s = 0.f;
        for (int c = 0; c < CC; c++) s += lxm[c * VV + tid];
        ls[tid] = s * (1.f / CC);
    }
    if (tid < RR * VV) {
        int r = tid / VV, v = tid % VV;
        float s1 = b1[r], s2 = b2[r];
        for (int c = 0; c < CC; c++) {
            float xv = lxm[c * VV + v];
            s1 += w1[r * CC + c] * xv;
            s2 += w2[r * CC + c] * xv;
        }
        l1[tid] = s1;
        l2[tid] = s2;
    }
    __syncthreads();

    if (tid < HH) {
        float h = sb1[tid];
        for (int v = 0; v < VV; v++) h += sw1[tid * VV + v] * ls[v];
        lh[tid] = fmaxf(h, 0.f);
    }
    __syncthreads();

    if (tid < VV) {
        float z = sb2[tid];
        for (int j = 0; j < HH; j++) z += sw2[tid * HH + j] * lh[j];
        la[tid] = 1.f / (1.f + expf(-z));
    }
    for (int idx = tid; idx < RR * VV * VV; idx += 256) {
        int r = idx / (VV * VV);
        int rem = idx % (VV * VV);
        int u = rem / VV, v = rem % VV;
        lrel[idx] = tanhf(l1[r * VV + u] - l2[r * VV + v]);
    }
    __syncthreads();

    // Ad' build: 32 channels, one padded quad (4 elems) per thread (tid<196)
    if (tid < ADSZ / 4) {
        const int c0 = chalf * 32;
        for (int ci = 0; ci < 32; ci++) {
            const int c = c0 + ci;
            const float b4c = lb4[c];
            const float* w4c = &lw4[c * RR];
            float4 q;
            float* qe = (float*)&q;
#pragma unroll
            for (int k = 0; k < 4; k++) {
                int uv = tid * 4 + k;
                int u = uv / 28, v = uv - u * 28;
                float val = 0.f;
                if (u < VV && v < VV) {
                    int e = u * VV + v;
                    val = b4c + lA[e];
#pragma unroll
                    for (int r = 0; r < RR; r++) val += w4c[r] * lrel[r * VV * VV + e];
                    val *= la[v];
                }
                qe[k] = val;
            }
            ((float4*)(ad_ws + ((size_t)n * CC + c) * ADSZ))[tid] = q;
        }
    }
}

// ---------------------------------------------------------------------------
// Kernel C2: per-(n,c) output tile.  out[t,u] = sum_v Ad'[u,v] * x[t,v]
// Ad' tile loaded from ws (one b128/thread). x staged transposed [v][t],
// stride TPAD=132 (conflict-free b128 reads). 4x4 register tile/thread.
// Epilogue via LDS for coalesced float4 stores (R2 lesson: direct scalar
// stores with 400 B lane stride cost ~48 cyc/instr in TA coalescing).
// ---------------------------------------------------------------------------
__global__ __launch_bounds__(256) void kC_main(
    const float* __restrict__ x, const float* __restrict__ ad_ws,
    float* __restrict__ out) {
    const int blk = blockIdx.x;    // n*CC + c
    const int tid = threadIdx.x;

    __shared__ float ad[ADSZ];          // 3136 B
    __shared__ float xs[28 * TPAD];     // 14784 B (>= 3200 for os reuse)
    float* os = xs;                     // output staging, reuses xs after phase 2

    // load Ad' tile (coalesced, mostly L2/L3-hit)
    if (tid < ADSZ / 4)
        ((float4*)ad)[tid] = ((const float4*)(ad_ws + (size_t)blk * ADSZ))[tid];

    // stage x tile TRANSPOSED (coalesced global float4 read, scalar LDS
    // writes xs[v][t]; ~4-way write conflicts, cheap)
    const float4* xb4 = (const float4*)(x + (size_t)blk * (TT * VV));
    for (int i = tid; i < (TT * VV) / 4; i += 256) {
        float4 q = xb4[i];
        int lin = i * 4;
        float vals[4] = {q.x, q.y, q.z, q.w};
#pragma unroll
        for (int k = 0; k < 4; k++) {
            int l = lin + k;
            int t = l / VV, v = l - t * VV;
            xs[v * TPAD + t] = vals[k];
        }
    }
    for (int i = tid; i < 3 * TPAD; i += 256) xs[25 * TPAD + i] = 0.f;
    __syncthreads();

    // phase 2: 4x4 register tile, conflict-free/broadcast LDS reads
    const int ug = tid >> 5;       // 0..7 (active < 7)
    const int tg = tid & 31;       // 0..31
    const int u0 = ug * 4;
    const int t0 = tg * 4;
    float acc[4][4];               // acc[dt][j]
#pragma unroll
    for (int dt = 0; dt < 4; dt++)
#pragma unroll
        for (int j = 0; j < 4; j++) acc[dt][j] = 0.f;

    if (ug < 7) {
#pragma unroll
        for (int vb = 0; vb < 7; vb++) {
            float4 a4[4];          // a4[j] = ad[u0+j][vb*4 .. +3]  (broadcast)
            float4 x4[4];          // x4[vi] = xs[vb*4+vi][t0 .. t0+3]
#pragma unroll
            for (int j = 0; j < 4; j++) a4[j] = *(const float4*)&ad[(u0 + j) * 28 + vb * 4];
#pragma unroll
            for (int vi = 0; vi < 4; vi++) x4[vi] = *(const float4*)&xs[(vb * 4 + vi) * TPAD + t0];
            const float* xv = (const float*)&x4[0];
#pragma unroll
            for (int dt = 0; dt < 4; dt++) {
#pragma unroll
                for (int j = 0; j < 4; j++) {
                    acc[dt][j] += a4[j].x * xv[0 * 4 + dt];
                    acc[dt][j] += a4[j].y * xv[1 * 4 + dt];
                    acc[dt][j] += a4[j].z * xv[2 * 4 + dt];
                    acc[dt][j] += a4[j].w * xv[3 * 4 + dt];
                }
            }
        }
    }
    __syncthreads();   // all xs reads done; safe to overwrite with os

    // epilogue a: scatter acc into os with exact output-tile layout
    if (ug < 7) {
#pragma unroll
        for (int dt = 0; dt < 4; dt++) {
#pragma unroll
            for (int j = 0; j < 4; j++) {
                int u = u0 + j;
                if (u < VV) os[(t0 + dt) * VV + u] = acc[dt][j];
            }
        }
    }
    __syncthreads();

    // epilogue b: coalesced float4 stores of the whole 12.8 KB tile
    float4* ob4 = (float4*)(out + (size_t)blk * (TT * VV));
    const float4* os4 = (const float4*)os;
    for (int i = tid; i < (TT * VV) / 4; i += 256) ob4[i] = os4[i];
}

// ---------------------------------------------------------------------------
extern "C" void kernel_launch(void* const* d_in, const int* in_sizes, int n_in,
                              void* d_out, int out_size, void* d_ws, size_t ws_size,
                              hipStream_t stream) {
    const float* x   = (const float*)d_in[0];
    const float* A   = (const float*)d_in[1];
    const float* w1  = (const float*)d_in[2];
    const float* b1  = (const float*)d_in[3];
    const float* w2  = (const float*)d_in[4];
    const float* b2  = (const float*)d_in[5];
    const float* w4  = (const float*)d_in[6];
    const float* b4  = (const float*)d_in[7];
    const float* sw1 = (const float*)d_in[8];
    const float* sb1 = (const float*)d_in[9];
    const float* sw2 = (const float*)d_in[10];
    const float* sb2 = (const float*)d_in[11];
    float* out = (float*)d_out;

    float* ws = (float*)d_ws;
    float* ad_ws = ws;                                   // N*C*784 = 6,422,528 floats (25.7 MB)
    float* xm    = ad_ws + (size_t)NN * CC * ADSZ;       // N*C*V   = 204,800 floats

    kA_tmean<<<NN * CC, 256, 0, stream>>>(x, xm);
    kB2_adbuild<<<NN * 2, 256, 0, stream>>>(xm, A, w1, b1, w2, b2, w4, b4,
                                            sw1, sb1, sw2, sb2, ad_ws);
    kC_main<<<NN * CC, 256, 0, stream>>>(x, ad_ws, out);
}